// Round 3
// baseline (150.316 us; speedup 1.0000x reference)
//
#include <hip/hip_runtime.h>

typedef short short8 __attribute__((ext_vector_type(8)));
typedef float f32x4 __attribute__((ext_vector_type(4)));

#define NN 4096
#define NE 512
#define HD 64
#define KROWS 4288   // 64 pad + 4096 + 128 pad  (per batch)
#define KOFF  64

// --- bf16 helpers: truncation hi/lo split; hi+lo == f to ~2^-17 rel ---
__device__ __forceinline__ unsigned short bf_trunc(float f) {
    union { float f; unsigned u; } c; c.f = f;
    return (unsigned short)(c.u >> 16);
}
__device__ __forceinline__ float bf_tof(unsigned short h) {
    union { float f; unsigned u; } c; c.u = ((unsigned)h) << 16;
    return c.f;
}
__device__ __forceinline__ void bf_split(float f, unsigned short& hi, unsigned short& lo) {
    union { float f; unsigned u; } c; c.f = f;
    unsigned uh = c.u & 0xFFFF0000u;
    hi = (unsigned short)(uh >> 16);
    union { float f; unsigned u; } d; d.u = uh;
    lo = bf_trunc(f - d.f);
}

#define MFMA16(a, b, c) __builtin_amdgcn_mfma_f32_16x16x32_bf16((a), (b), (c), 0, 0, 0)

// ---------------------------------------------------------------------------
// wprep: swizzle W=[Wq|Wk|Wv] (512x192) into B-frag order, hi/lo bf16.
// Layout: [kt(16)][nt(12)][lane(64)][j(8)], elem = W[kt*32+(L>>4)*8+j][nt*16+(L&15)]
// ---------------------------------------------------------------------------
__global__ __launch_bounds__(256) void wprep_kernel(
    const float* __restrict__ Wq, const float* __restrict__ Wk,
    const float* __restrict__ Wv,
    unsigned short* __restrict__ Wfhi, unsigned short* __restrict__ Wflo)
{
    const int tid = blockIdx.x * 256 + threadIdx.x;   // [0, 12288)
    const int L = tid & 63;
    const int nt = (tid >> 6) % 12;
    const int kt = tid / 768;
    const int n = nt * 16 + (L & 15);
    const int kbase = kt * 32 + (L >> 4) * 8;
    const float* src; int col;
    if (n < 64)       { src = Wq; col = n; }
    else if (n < 128) { src = Wk; col = n - 64; }
    else              { src = Wv; col = n - 128; }
    short8 sh, sl;
#pragma unroll
    for (int j = 0; j < 8; ++j) {
        unsigned short h, l;
        bf_split(src[(size_t)(kbase + j) * HD + col], h, l);
        sh[j] = (short)h; sl[j] = (short)l;
    }
    *(short8*)(Wfhi + (size_t)tid * 8) = sh;
    *(short8*)(Wflo + (size_t)tid * 8) = sl;
}

// ---------------------------------------------------------------------------
// proj: QKV = x @ W + b via 3-pass bf16 MFMA. grid 128, block 512 (8 waves).
// Wave (w>>1) = 16-row tile of 64-row block; (w&1) = 96-col half of 192 cols.
// Outputs: Qhi/Qlo bf16 row-major; Khi/Klo bf16 into padded buffer;
// V fp32 rows 0..128 only; Vsum fp32 via block-reduce + atomics.
// ---------------------------------------------------------------------------
__global__ __launch_bounds__(512) void proj_kernel(
    const float* __restrict__ x,
    const unsigned short* __restrict__ Wfhi, const unsigned short* __restrict__ Wflo,
    const float* __restrict__ bq, const float* __restrict__ bk,
    const float* __restrict__ bv,
    unsigned short* __restrict__ Qhi, unsigned short* __restrict__ Qlo,
    unsigned short* __restrict__ Khi, unsigned short* __restrict__ Klo,
    float* __restrict__ V129, float* __restrict__ Vs)
{
    __shared__ float vred[16][64];
    const int tid = threadIdx.x;
    const int L = tid & 63;
    const int w = tid >> 6;              // wave 0..7
    const int m  = L & 15;               // row-in-tile / col-in-tile
    const int kg = L >> 4;               // k-group 0..3
    const int r0 = blockIdx.x * 64;
    const int rowbase = r0 + (w >> 1) * 16;
    const int colhalf = (w & 1) * 6;     // first of 6 ntiles

    f32x4 acc[6];
#pragma unroll
    for (int t = 0; t < 6; ++t) acc[t] = (f32x4){0.f, 0.f, 0.f, 0.f};

    for (int kt = 0; kt < 16; ++kt) {
        // A-frag: x[rowbase+m][kt*32 + kg*8 .. +7], fp32 -> hi/lo bf16
        const float* xp = x + (size_t)(rowbase + m) * NE + kt * 32 + kg * 8;
        const float4 a0 = *(const float4*)xp;
        const float4 a1 = *(const float4*)(xp + 4);
        float xv[8] = {a0.x, a0.y, a0.z, a0.w, a1.x, a1.y, a1.z, a1.w};
        short8 ahi, alo;
#pragma unroll
        for (int j = 0; j < 8; ++j) {
            unsigned short h, l; bf_split(xv[j], h, l);
            ahi[j] = (short)h; alo[j] = (short)l;
        }
#pragma unroll
        for (int t = 0; t < 6; ++t) {
            const size_t fo = ((size_t)(kt * 12 + colhalf + t) * 64 + L) * 8;
            const short8 bhi = *(const short8*)(Wfhi + fo);
            const short8 blo = *(const short8*)(Wflo + fo);
            acc[t] = MFMA16(ahi, bhi, acc[t]);
            acc[t] = MFMA16(alo, bhi, acc[t]);
            acc[t] = MFMA16(ahi, blo, acc[t]);
        }
    }

    const int b = r0 >> 12;              // batch (64-row blocks never straddle)
#pragma unroll
    for (int t = 0; t < 6; ++t) {
        const int cg = (colhalf + t) * 16 + m;   // global col 0..191
        const float bias = (cg < 64) ? bq[cg] : (cg < 128) ? bk[cg - 64] : bv[cg - 128];
        float vsump = 0.f;
#pragma unroll
        for (int r = 0; r < 4; ++r) {
            const int gr = rowbase + kg * 4 + r;
            const float val = acc[t][r] + bias;
            if (cg < 64) {
                unsigned short h, l; bf_split(val, h, l);
                Qhi[(size_t)gr * HD + cg] = h;
                Qlo[(size_t)gr * HD + cg] = l;
            } else if (cg < 128) {
                const int d = cg - 64, n = gr & 4095;
                const size_t idx = ((size_t)b * KROWS + KOFF + n) * HD + d;
                unsigned short h, l; bf_split(val, h, l);
                Khi[idx] = h; Klo[idx] = l;
            } else {
                const int d = cg - 128, n = gr & 4095;
                vsump += val;
                if (n < 129) V129[((size_t)b * 129 + n) * HD + d] = val;
            }
        }
        if (cg >= 128) vred[(w >> 1) * 4 + kg][cg - 128] = vsump;
    }
    __syncthreads();
    if (tid < 64) {
        float s = 0.f;
#pragma unroll
        for (int g = 0; g < 16; ++g) s += vred[g][tid];
        atomicAdd(&Vs[b * HD + tid], s);
    }
}

// ---------------------------------------------------------------------------
// vprep: swizzle P = [V[0:129] | ones | 0] (160x80) into B-frag order hi/lo.
// Layout: [b(2)][jt(5)][nt(5)][lane(64)][jj(8)]
// ---------------------------------------------------------------------------
__global__ __launch_bounds__(256) void vprep_kernel(
    const float* __restrict__ V129,
    unsigned short* __restrict__ Vfhi, unsigned short* __restrict__ Vflo)
{
    const int tid = blockIdx.x * 256 + threadIdx.x;
    if (tid >= 3200) return;
    const int L = tid & 63;
    const int nt = (tid >> 6) % 5;
    const int jt = (tid / 320) % 5;
    const int b  = tid / 1600;
    const int n  = nt * 16 + (L & 15);
    const int jb = jt * 32 + (L >> 4) * 8;
    short8 sh, sl;
#pragma unroll
    for (int jj = 0; jj < 8; ++jj) {
        const int j = jb + jj;
        float val = 0.f;
        if (j < 129) {
            if (n < 64)       val = V129[((size_t)b * 129 + j) * HD + n];
            else if (n == 64) val = 1.0f;
        }
        unsigned short h, l; bf_split(val, h, l);
        sh[jj] = (short)h; sl[jj] = (short)l;
    }
    *(short8*)(Vfhi + (size_t)tid * 8) = sh;
    *(short8*)(Vflo + (size_t)tid * 8) = sl;
}

// ---------------------------------------------------------------------------
// attn: grid 512 (b = blk>>8, 16 queries/block), block 256 (4 waves).
// Phase 1: S = Q(16x64)·K^T via MFMA, frags straight from global (zero-padded
// K makes OOB keys give s=0 -> w=0 exactly). w=exp(s)-1 -> wt_lds (q,j) hi/lo.
// Phase 2: [out|den] = wt(16x160) @ [V|1|0](160x80) via MFMA, wave w owns
// out-ntile w; wave 0 also computes the ones-column (denominator) tile.
// ---------------------------------------------------------------------------
__global__ __launch_bounds__(256) void attn_kernel(
    const unsigned short* __restrict__ Qhi, const unsigned short* __restrict__ Qlo,
    const unsigned short* __restrict__ Khi, const unsigned short* __restrict__ Klo,
    const unsigned short* __restrict__ Vfhi, const unsigned short* __restrict__ Vflo,
    const float* __restrict__ Vs, float* __restrict__ out)
{
    __shared__ __align__(16) unsigned short wt_hi[16 * 168];
    __shared__ __align__(16) unsigned short wt_lo[16 * 168];
    __shared__ float den_lds[16];

    const int tid = threadIdx.x;
    const int L = tid & 63;
    const int w = tid >> 6;
    const int m  = L & 15;
    const int kg = L >> 4;
    const int b  = blockIdx.x >> 8;
    const int n0 = (blockIdx.x & 255) * 16;

    // zero the (q,j) weight shear buffer (j in [129,160) must be 0)
    for (int i = tid; i < (16 * 168) / 2; i += 256) {
        ((int*)wt_hi)[i] = 0;
        ((int*)wt_lo)[i] = 0;
    }
    __syncthreads();

    // ---- phase 1 ----
    const unsigned short* qp  = Qhi + ((size_t)(b * NN + n0 + m)) * HD + kg * 8;
    const unsigned short* qp2 = Qlo + ((size_t)(b * NN + n0 + m)) * HD + kg * 8;
    const short8 qhi0 = *(const short8*)(qp);
    const short8 qhi1 = *(const short8*)(qp + 32);
    const short8 qlo0 = *(const short8*)(qp2);
    const short8 qlo1 = *(const short8*)(qp2 + 32);

    const unsigned short* KB  = Khi + (size_t)b * KROWS * HD;  // row 0 == key n0-64
    const unsigned short* KB2 = Klo + (size_t)b * KROWS * HD;

    int ktl[3]; int nkt;
    if (w == 0) { ktl[0] = 0; ktl[1] = 4; ktl[2] = 8; nkt = 3; }
    else        { ktl[0] = w; ktl[1] = w + 4; ktl[2] = 0; nkt = 2; }

    for (int i = 0; i < nkt; ++i) {
        const int kt = ktl[i];
        // buffer row = (n0-64+l) + KOFF = n0 + l, l = kt*16+m
        const size_t krow = (size_t)(n0 + kt * 16 + m);
        const unsigned short* kp  = KB  + krow * HD + kg * 8;
        const unsigned short* kp2 = KB2 + krow * HD + kg * 8;
        const short8 khi0 = *(const short8*)(kp);
        const short8 khi1 = *(const short8*)(kp + 32);
        const short8 klo0 = *(const short8*)(kp2);
        const short8 klo1 = *(const short8*)(kp2 + 32);
        f32x4 acc = (f32x4){0.f, 0.f, 0.f, 0.f};
        acc = MFMA16(qhi0, khi0, acc);
        acc = MFMA16(qhi1, khi1, acc);
        acc = MFMA16(qlo0, khi0, acc);
        acc = MFMA16(qlo1, khi1, acc);
        acc = MFMA16(qhi0, klo0, acc);
        acc = MFMA16(qhi1, klo1, acc);
#pragma unroll
        for (int r = 0; r < 4; ++r) {
            const int q = kg * 4 + r;
            const int l = kt * 16 + m;
            const int j = l - q;
            if (j >= 0 && j < 129) {
                const float wv = __expf(acc[r]) - 1.0f;
                unsigned short h, lo2; bf_split(wv, h, lo2);
                wt_hi[q * 168 + j] = h;
                wt_lo[q * 168 + j] = lo2;
            }
        }
    }
    __syncthreads();

    // ---- phase 2 ----
    f32x4 oacc = (f32x4){0.f, 0.f, 0.f, 0.f};
    f32x4 dacc = (f32x4){0.f, 0.f, 0.f, 0.f};
    const int nt = w;                    // output ntile
    for (int jt = 0; jt < 5; ++jt) {
        const short8 whi = *(const short8*)(wt_hi + m * 168 + jt * 32 + kg * 8);
        const short8 wlo = *(const short8*)(wt_lo + m * 168 + jt * 32 + kg * 8);
        const size_t fo = ((size_t)((b * 25 + jt * 5 + nt) * 64 + L)) * 8;
        const short8 vhi = *(const short8*)(Vfhi + fo);
        const short8 vlo = *(const short8*)(Vflo + fo);
        oacc = MFMA16(whi, vhi, oacc);
        oacc = MFMA16(wlo, vhi, oacc);
        oacc = MFMA16(whi, vlo, oacc);
        if (w == 0) {
            const size_t fo4 = ((size_t)((b * 25 + jt * 5 + 4) * 64 + L)) * 8;
            const short8 vh4 = *(const short8*)(Vfhi + fo4);
            dacc = MFMA16(whi, vh4, dacc);
            dacc = MFMA16(wlo, vh4, dacc);   // ones col exact in hi; lo tile = 0
        }
    }
    if (w == 0 && m == 0) {
#pragma unroll
        for (int r = 0; r < 4; ++r) den_lds[kg * 4 + r] = dacc[r];
    }
    __syncthreads();

    // ---- epilogue ----
    {
        const float vs = Vs[b * HD + nt * 16 + m];
#pragma unroll
        for (int r = 0; r < 4; ++r) {
            const int q = kg * 4 + r;
            const float val = (vs + oacc[r]) / (4096.f + den_lds[q]);
            out[((size_t)(b * NN + n0 + q)) * HD + nt * 16 + m] = val;
        }
    }
}

// ---------------------------------------------------------------------------
extern "C" void kernel_launch(void* const* d_in, const int* in_sizes, int n_in,
                              void* d_out, int out_size, void* d_ws, size_t ws_size,
                              hipStream_t stream)
{
    const float* x  = (const float*)d_in[0];
    const float* Wq = (const float*)d_in[1];
    const float* bq = (const float*)d_in[2];
    const float* Wk = (const float*)d_in[3];
    const float* bk = (const float*)d_in[4];
    const float* Wv = (const float*)d_in[5];
    const float* bv = (const float*)d_in[6];
    float* out = (float*)d_out;

    char* ws = (char*)d_ws;
    float*          Vs   = (float*)(ws + 0);                  //      512 B
    unsigned short* Khi  = (unsigned short*)(ws + 512);       // 1097728 B
    unsigned short* Klo  = (unsigned short*)(ws + 1098240);   // 1097728 B
    unsigned short* Qhi  = (unsigned short*)(ws + 2195968);   // 1048576 B
    unsigned short* Qlo  = (unsigned short*)(ws + 3244544);   // 1048576 B
    float*          V129 = (float*)(ws + 4293120);            //   66048 B
    unsigned short* Wfhi = (unsigned short*)(ws + 4359168);   //  196608 B
    unsigned short* Wflo = (unsigned short*)(ws + 4555776);   //  196608 B
    unsigned short* Vfhi = (unsigned short*)(ws + 4752384);   //   51200 B
    unsigned short* Vflo = (unsigned short*)(ws + 4803584);   //   51200 B

    // zero Vs + Khi + Klo (K pads must read as 0 -> w=0 for OOB keys)
    hipMemsetAsync(d_ws, 0, 2195968, stream);
    wprep_kernel<<<48, 256, 0, stream>>>(Wq, Wk, Wv, Wfhi, Wflo);
    proj_kernel<<<128, 512, 0, stream>>>(x, Wfhi, Wflo, bq, bk, bv,
                                         Qhi, Qlo, Khi, Klo, V129, Vs);
    vprep_kernel<<<13, 256, 0, stream>>>(V129, Vfhi, Vflo);
    attn_kernel<<<512, 256, 0, stream>>>(Qhi, Qlo, Khi, Klo, Vfhi, Vflo, Vs, out);
}

// Round 5
// 102.272 us; speedup vs baseline: 1.4698x; 1.4698x over previous
//
#include <hip/hip_runtime.h>

typedef short short8 __attribute__((ext_vector_type(8)));
typedef float f32x4 __attribute__((ext_vector_type(4)));

#define NN 4096
#define NE 512
#define HD 64
#define KROWS 4288   // 64 pad + 4096 + 128 pad (per batch)
#define KOFF  64

// --- bf16 helpers: truncation hi/lo split; hi+lo == f to ~2^-17 rel ---
__device__ __forceinline__ unsigned short bf_trunc(float f) {
    union { float f; unsigned u; } c; c.f = f;
    return (unsigned short)(c.u >> 16);
}
__device__ __forceinline__ void bf_split(float f, unsigned short& hi, unsigned short& lo) {
    union { float f; unsigned u; } c; c.f = f;
    unsigned uh = c.u & 0xFFFF0000u;
    hi = (unsigned short)(uh >> 16);
    union { float f; unsigned u; } d; d.u = uh;
    lo = bf_trunc(f - d.f);
}

#define MFMA16(a, b, c) __builtin_amdgcn_mfma_f32_16x16x32_bf16((a), (b), (c), 0, 0, 0)

// ---------------------------------------------------------------------------
// wprep: (a) swizzle W=[Wq|Wk|Wv] (512x192) into B-frag order, hi AND lo
//        (lo is needed: W ~ +-0.044, bf16-only W costs 5x output error).
//        (b) zero the K-buffer pad rows (hi+lo) and Vs (re-poisoned/launch).
// Frag layout: [kt(16)][nt(12)][lane(64)][j(8)],
//   elem = W[kt*32+(L>>4)*8+j][nt*16+(L&15)]
// ---------------------------------------------------------------------------
__global__ __launch_bounds__(256) void wprep_kernel(
    const float* __restrict__ Wq, const float* __restrict__ Wk,
    const float* __restrict__ Wv,
    unsigned short* __restrict__ Wfhi, unsigned short* __restrict__ Wflo,
    unsigned short* __restrict__ Khi, unsigned short* __restrict__ Klo,
    float* __restrict__ Vs)
{
    const int gtid = blockIdx.x * 256 + threadIdx.x;   // [0, 12288)
    {
        const int L = gtid & 63;
        const int nt = (gtid >> 6) % 12;
        const int kt = gtid / 768;
        const int n = nt * 16 + (L & 15);
        const int kbase = kt * 32 + (L >> 4) * 8;
        const float* src; int col;
        if (n < 64)       { src = Wq; col = n; }
        else if (n < 128) { src = Wk; col = n - 64; }
        else              { src = Wv; col = n - 128; }
        short8 sh, sl;
#pragma unroll
        for (int j = 0; j < 8; ++j) {
            unsigned short h, l;
            bf_split(src[(size_t)(kbase + j) * HD + col], h, l);
            sh[j] = (short)h; sl[j] = (short)l;
        }
        *(short8*)(Wfhi + (size_t)gtid * 8) = sh;
        *(short8*)(Wflo + (size_t)gtid * 8) = sl;
    }
    // pad zeroing: 768 pad rows x 128 B, 16 B per thread -> 6144 threads
    if (gtid < 6144) {
        const int p = gtid >> 3, o = gtid & 7;
        const int b = p / 192, q = p - b * 192;
        const size_t row = (size_t)b * KROWS + (q < 64 ? q : 4096 + q);
        const short8 z = {0, 0, 0, 0, 0, 0, 0, 0};
        *(short8*)(Khi + row * HD + o * 8) = z;
        *(short8*)(Klo + row * HD + o * 8) = z;
    }
    if (gtid < 128) Vs[gtid] = 0.f;
}

// ---------------------------------------------------------------------------
// proj: QKV = x @ W + b, 3-pass bf16 MFMA (ahi*Whi + alo*Whi + ahi*Wlo).
// grid 256, block 512 (8 waves): rt = w&1 (16-row tile of 32), cg3 = w>>1
// (3 ntiles). Register double-buffered x + W-frag pipeline, NO k-loop
// barriers -> waves run free, loads one full chunk ahead.
// ---------------------------------------------------------------------------
__global__ __launch_bounds__(512) void proj_kernel(
    const float* __restrict__ x,
    const unsigned short* __restrict__ Wfhi, const unsigned short* __restrict__ Wflo,
    const float* __restrict__ bq, const float* __restrict__ bk,
    const float* __restrict__ bv,
    unsigned short* __restrict__ Qhi, unsigned short* __restrict__ Qlo,
    unsigned short* __restrict__ Khi, unsigned short* __restrict__ Klo,
    float* __restrict__ V129, float* __restrict__ Vs)
{
    __shared__ float vred[8][64];
    const int tid = threadIdx.x;
    const int L = tid & 63;
    const int w = tid >> 6;
    const int rt = w & 1, cg3 = w >> 1;
    const int m = L & 15, kg = L >> 4;
    const int r0 = blockIdx.x * 32;
    const int rowbase = r0 + rt * 16;

    const float* xp_base = x + (size_t)(rowbase + m) * NE + kg * 8;
    const unsigned short* wfh_base = Wfhi + (size_t)(cg3 * 3) * 512 + L * 8;
    const unsigned short* wfl_base = Wflo + (size_t)(cg3 * 3) * 512 + L * 8;

    f32x4 acc[3];
#pragma unroll
    for (int t = 0; t < 3; ++t) acc[t] = (f32x4){0.f, 0.f, 0.f, 0.f};

    // prologue: chunk-0 loads
    float4 xa0 = *(const float4*)(xp_base);
    float4 xa1 = *(const float4*)(xp_base + 4);
    short8 wh0 = *(const short8*)(wfh_base + 0 * 512);
    short8 wh1 = *(const short8*)(wfh_base + 1 * 512);
    short8 wh2 = *(const short8*)(wfh_base + 2 * 512);
    short8 wl0 = *(const short8*)(wfl_base + 0 * 512);
    short8 wl1 = *(const short8*)(wfl_base + 1 * 512);
    short8 wl2 = *(const short8*)(wfl_base + 2 * 512);

    for (int kt = 0; kt < 16; ++kt) {
        // issue next chunk's loads (clamped at the end; dup load is harmless)
        const int ktn = (kt < 15) ? kt + 1 : 15;
        const float* xn = xp_base + ktn * 32;
        const float4 xb0 = *(const float4*)(xn);
        const float4 xb1 = *(const float4*)(xn + 4);
        const unsigned short* wnh = wfh_base + (size_t)ktn * 6144;
        const unsigned short* wnl = wfl_base + (size_t)ktn * 6144;
        const short8 nh0 = *(const short8*)(wnh);
        const short8 nh1 = *(const short8*)(wnh + 512);
        const short8 nh2 = *(const short8*)(wnh + 1024);
        const short8 nl0 = *(const short8*)(wnl);
        const short8 nl1 = *(const short8*)(wnl + 512);
        const short8 nl2 = *(const short8*)(wnl + 1024);

        const float xv[8] = {xa0.x, xa0.y, xa0.z, xa0.w,
                             xa1.x, xa1.y, xa1.z, xa1.w};
        short8 ahi, alo;
#pragma unroll
        for (int j = 0; j < 8; ++j) {
            unsigned short h, l; bf_split(xv[j], h, l);
            ahi[j] = (short)h; alo[j] = (short)l;
        }
        acc[0] = MFMA16(ahi, wh0, acc[0]);
        acc[0] = MFMA16(alo, wh0, acc[0]);
        acc[0] = MFMA16(ahi, wl0, acc[0]);
        acc[1] = MFMA16(ahi, wh1, acc[1]);
        acc[1] = MFMA16(alo, wh1, acc[1]);
        acc[1] = MFMA16(ahi, wl1, acc[1]);
        acc[2] = MFMA16(ahi, wh2, acc[2]);
        acc[2] = MFMA16(alo, wh2, acc[2]);
        acc[2] = MFMA16(ahi, wl2, acc[2]);

        xa0 = xb0; xa1 = xb1;
        wh0 = nh0; wh1 = nh1; wh2 = nh2;
        wl0 = nl0; wl1 = nl1; wl2 = nl2;
    }

    const int b = r0 >> 12;
#pragma unroll
    for (int t = 0; t < 3; ++t) {
        const int nt = cg3 * 3 + t;
        const int cg = nt * 16 + m;      // global col 0..191 (type uniform per t)
        const float bias = (cg < 64) ? bq[cg] : (cg < 128) ? bk[cg - 64] : bv[cg - 128];
        float vsump = 0.f;
#pragma unroll
        for (int r = 0; r < 4; ++r) {
            const int gr = rowbase + kg * 4 + r;
            const float val = acc[t][r] + bias;
            if (cg < 64) {
                unsigned short h, l; bf_split(val, h, l);
                Qhi[(size_t)gr * HD + cg] = h;
                Qlo[(size_t)gr * HD + cg] = l;
            } else if (cg < 128) {
                const int d = cg - 64, n = gr & 4095;
                const size_t idx = ((size_t)b * KROWS + KOFF + n) * HD + d;
                unsigned short h, l; bf_split(val, h, l);
                Khi[idx] = h; Klo[idx] = l;
            } else {
                const int d = cg - 128, n = gr & 4095;
                vsump += val;
                if (n < 129) V129[((size_t)b * 129 + n) * HD + d] = val;
            }
        }
        if (cg >= 128) vred[rt * 4 + kg][cg - 128] = vsump;
    }
    __syncthreads();
    if (tid < 64) {
        float s = 0.f;
#pragma unroll
        for (int g = 0; g < 8; ++g) s += vred[g][tid];
        atomicAdd(&Vs[b * HD + tid], s);
    }
}

// ---------------------------------------------------------------------------
// vprep: swizzle P = [V[0:129] | ones | 0] (160x80) into B-frag order hi/lo.
// Layout: [b(2)][jt(5)][nt(5)][lane(64)][jj(8)]
// ---------------------------------------------------------------------------
__global__ __launch_bounds__(256) void vprep_kernel(
    const float* __restrict__ V129,
    unsigned short* __restrict__ Vfhi, unsigned short* __restrict__ Vflo)
{
    const int tid = blockIdx.x * 256 + threadIdx.x;
    if (tid >= 3200) return;
    const int L = tid & 63;
    const int nt = (tid >> 6) % 5;
    const int jt = (tid / 320) % 5;
    const int b  = tid / 1600;
    const int n  = nt * 16 + (L & 15);
    const int jb = jt * 32 + (L >> 4) * 8;
    short8 sh, sl;
#pragma unroll
    for (int jj = 0; jj < 8; ++jj) {
        const int j = jb + jj;
        float val = 0.f;
        if (j < 129) {
            if (n < 64)       val = V129[((size_t)b * 129 + j) * HD + n];
            else if (n == 64) val = 1.0f;
        }
        unsigned short h, l; bf_split(val, h, l);
        sh[jj] = (short)h; sl[jj] = (short)l;
    }
    *(short8*)(Vfhi + (size_t)tid * 8) = sh;
    *(short8*)(Vflo + (size_t)tid * 8) = sl;
}

// ---------------------------------------------------------------------------
// attn: grid 512 (b = blk>>8, 16 queries/block), block 256 (4 waves).
// ALL global loads (Q frags, K frags, V frags) issued up front into
// registers -> one latency hop, max MLP. Phase 1: S = Q.K^T (3-pass),
// w = exp(s)-1 scattered to LDS (q,j) hi/lo. Phase 2: [out|den] =
// wt(16x160) @ [V|1|0] (3-pass); wave w owns ntile w; wave 0 also den.
// ---------------------------------------------------------------------------
__global__ __launch_bounds__(256) void attn_kernel(
    const unsigned short* __restrict__ Qhi, const unsigned short* __restrict__ Qlo,
    const unsigned short* __restrict__ Khi, const unsigned short* __restrict__ Klo,
    const unsigned short* __restrict__ Vfhi, const unsigned short* __restrict__ Vflo,
    const float* __restrict__ Vs, float* __restrict__ out)
{
    __shared__ __align__(16) unsigned short wt_hi[16 * 168];
    __shared__ __align__(16) unsigned short wt_lo[16 * 168];
    __shared__ float den_lds[16];

    const int tid = threadIdx.x;
    const int L = tid & 63;
    const int w = tid >> 6;
    const int m = L & 15, kg = L >> 4;
    const int b = blockIdx.x >> 8;
    const int n0 = (blockIdx.x & 255) * 16;

    // ---- upfront load issuance (all independent) ----
    const unsigned short* qp  = Qhi + ((size_t)(b * NN + n0 + m)) * HD + kg * 8;
    const unsigned short* qp2 = Qlo + ((size_t)(b * NN + n0 + m)) * HD + kg * 8;
    const short8 qhi0 = *(const short8*)(qp);
    const short8 qhi1 = *(const short8*)(qp + 32);
    const short8 qlo0 = *(const short8*)(qp2);
    const short8 qlo1 = *(const short8*)(qp2 + 32);

    int kts[3]; int nkt;
    if (w == 3) { kts[0] = 3; kts[1] = 7; kts[2] = 8; nkt = 3; }
    else        { kts[0] = w; kts[1] = w + 4; kts[2] = 0; nkt = 2; }

    const unsigned short* KB  = Khi + (size_t)b * KROWS * HD;
    const unsigned short* KB2 = Klo + (size_t)b * KROWS * HD;
    short8 kh0[3], kh1[3], kl0[3], kl1[3];
#pragma unroll
    for (int i = 0; i < 3; ++i) {
        if (i < nkt) {                       // wave-uniform branch
            const size_t krow = (size_t)(n0 + kts[i] * 16 + m);
            const unsigned short* kp  = KB  + krow * HD + kg * 8;
            const unsigned short* kp2 = KB2 + krow * HD + kg * 8;
            kh0[i] = *(const short8*)(kp);
            kh1[i] = *(const short8*)(kp + 32);
            kl0[i] = *(const short8*)(kp2);
            kl1[i] = *(const short8*)(kp2 + 32);
        }
    }

    short8 vhi[5], vlo[5], vh4[5];
#pragma unroll
    for (int jt = 0; jt < 5; ++jt) {
        const size_t fo = ((size_t)((b * 25 + jt * 5 + w) * 64 + L)) * 8;
        vhi[jt] = *(const short8*)(Vfhi + fo);
        vlo[jt] = *(const short8*)(Vflo + fo);
    }
    if (w == 0) {                            // wave-uniform
#pragma unroll
        for (int jt = 0; jt < 5; ++jt) {
            const size_t fo4 = ((size_t)((b * 25 + jt * 5 + 4) * 64 + L)) * 8;
            vh4[jt] = *(const short8*)(Vfhi + fo4);
        }
    }

    // zero the (q,j) weight buffer (j in [129,168) must read as 0)
    for (int i = tid; i < (16 * 168) / 2; i += 256) {
        ((int*)wt_hi)[i] = 0;
        ((int*)wt_lo)[i] = 0;
    }
    __syncthreads();

    // ---- phase 1 ----
#pragma unroll
    for (int i = 0; i < 3; ++i) {
        if (i < nkt) {
            f32x4 acc = (f32x4){0.f, 0.f, 0.f, 0.f};
            acc = MFMA16(qhi0, kh0[i], acc);
            acc = MFMA16(qhi1, kh1[i], acc);
            acc = MFMA16(qlo0, kh0[i], acc);
            acc = MFMA16(qlo1, kh1[i], acc);
            acc = MFMA16(qhi0, kl0[i], acc);
            acc = MFMA16(qhi1, kl1[i], acc);
            const int l = kts[i] * 16 + m;
#pragma unroll
            for (int r = 0; r < 4; ++r) {
                const int q = kg * 4 + r;
                const int j = l - q;
                if (j >= 0 && j < 129) {
                    const float wv = __expf(acc[r]) - 1.0f;
                    unsigned short h, lo2; bf_split(wv, h, lo2);
                    wt_hi[q * 168 + j] = h;
                    wt_lo[q * 168 + j] = lo2;
                }
            }
        }
    }
    __syncthreads();

    // ---- phase 2 ----
    f32x4 oacc = (f32x4){0.f, 0.f, 0.f, 0.f};
    f32x4 dacc = (f32x4){0.f, 0.f, 0.f, 0.f};
#pragma unroll
    for (int jt = 0; jt < 5; ++jt) {
        const short8 whi = *(const short8*)(wt_hi + m * 168 + jt * 32 + kg * 8);
        const short8 wlo = *(const short8*)(wt_lo + m * 168 + jt * 32 + kg * 8);
        oacc = MFMA16(whi, vhi[jt], oacc);
        oacc = MFMA16(wlo, vhi[jt], oacc);
        oacc = MFMA16(whi, vlo[jt], oacc);
        if (w == 0) {
            dacc = MFMA16(whi, vh4[jt], dacc);
            dacc = MFMA16(wlo, vh4[jt], dacc);
        }
    }
    if (w == 0 && m == 0) {
#pragma unroll
        for (int r = 0; r < 4; ++r) den_lds[kg * 4 + r] = dacc[r];
    }
    __syncthreads();

    // ---- epilogue ----
    {
        const float vs = Vs[b * HD + w * 16 + m];
#pragma unroll
        for (int r = 0; r < 4; ++r) {
            const int q = kg * 4 + r;
            const float val = (vs + oacc[r]) / (4096.f + den_lds[q]);
            out[((size_t)(b * NN + n0 + q)) * HD + w * 16 + m] = val;
        }
    }
}

// ---------------------------------------------------------------------------
extern "C" void kernel_launch(void* const* d_in, const int* in_sizes, int n_in,
                              void* d_out, int out_size, void* d_ws, size_t ws_size,
                              hipStream_t stream)
{
    const float* x  = (const float*)d_in[0];
    const float* Wq = (const float*)d_in[1];
    const float* bq = (const float*)d_in[2];
    const float* Wk = (const float*)d_in[3];
    const float* bk = (const float*)d_in[4];
    const float* Wv = (const float*)d_in[5];
    const float* bv = (const float*)d_in[6];
    float* out = (float*)d_out;

    char* ws = (char*)d_ws;
    float*          Vs   = (float*)(ws + 0);                  //      512 B
    unsigned short* Khi  = (unsigned short*)(ws + 512);       // 1097728 B
    unsigned short* Klo  = (unsigned short*)(ws + 1098240);   // 1097728 B
    unsigned short* Qhi  = (unsigned short*)(ws + 2195968);   // 1048576 B
    unsigned short* Qlo  = (unsigned short*)(ws + 3244544);   // 1048576 B
    float*          V129 = (float*)(ws + 4293120);            //   66048 B
    unsigned short* Wfhi = (unsigned short*)(ws + 4359168);   //  196608 B
    unsigned short* Wflo = (unsigned short*)(ws + 4555776);   //  196608 B
    unsigned short* Vfhi = (unsigned short*)(ws + 4752384);   //   51200 B
    unsigned short* Vflo = (unsigned short*)(ws + 4803584);   //   51200 B

    wprep_kernel<<<48, 256, 0, stream>>>(Wq, Wk, Wv, Wfhi, Wflo, Khi, Klo, Vs);
    proj_kernel<<<256, 512, 0, stream>>>(x, Wfhi, Wflo, bq, bk, bv,
                                         Qhi, Qlo, Khi, Klo, V129, Vs);
    vprep_kernel<<<13, 256, 0, stream>>>(V129, Vfhi, Vflo);
    attn_kernel<<<512, 256, 0, stream>>>(Qhi, Qlo, Khi, Klo, Vfhi, Vflo, Vs, out);
}